// Round 10
// baseline (275.068 us; speedup 1.0000x reference)
//
#include <hip/hip_runtime.h>
#include <hip/hip_bf16.h>

#define N_ATOMS 131072
#define DQ 256
#define H1 512
#define NTYPES 4
#define TILE_M 64
#define GRID 512    // persistent, 2/CU; static stride-512 tile schedule

typedef __bf16 bf16x8 __attribute__((ext_vector_type(8)));
typedef float f32x16 __attribute__((ext_vector_type(16)));

__device__ __forceinline__ unsigned short f2bf(float f) {
  unsigned int u = __builtin_bit_cast(unsigned int, f);
  u += 0x7fffu + ((u >> 16) & 1u);   // round-to-nearest-even (inputs finite)
  return (unsigned short)(u >> 16);
}

__device__ __forceinline__ float fast_tanh(float x) {
  float e = __expf(2.0f * x);
  return 1.0f - 2.0f * __builtin_amdgcn_rcpf(e + 1.0f);
}

// ---------------------------------------------------------------------------
// init: zero cnt[4] device-side (graph-capture safe)
// ---------------------------------------------------------------------------
__global__ __launch_bounds__(64) void init_kernel(int* __restrict__ hdr) {
  if (threadIdx.x < 16) hdr[threadIdx.x] = 0;
}

// ---------------------------------------------------------------------------
// prep (fused): (a) W0 fp32 -> bf16 pre-swizzled [t][k/8][n][8k],
// (b) block-aggregated scatter of atom ids into FIXED per-type perm regions
// (perm[t*N + j], j < cnt[t]).
// ---------------------------------------------------------------------------
__global__ __launch_bounds__(256) void prep_kernel(
    const float* __restrict__ W0, const int* __restrict__ Z,
    unsigned short* __restrict__ W0s, int* __restrict__ perm,
    int* __restrict__ cnt)
{
  const int b = blockIdx.x, tid = threadIdx.x;
  const int gid = b * 256 + tid;

  if (gid < NTYPES * (DQ / 8) * H1) {   // 65536 16-byte chunks
    const int n  = gid & (H1 - 1);
    const int kg = (gid >> 9) & 31;
    const int t  = gid >> 14;
    const float* src = W0 + ((size_t)(t * DQ + kg * 8) * H1 + n);
    unsigned short o[8];
#pragma unroll
    for (int j = 0; j < 8; ++j) o[j] = f2bf(src[(size_t)j * H1]);
    uint4 v;
    v.x = (unsigned)o[0] | ((unsigned)o[1] << 16);
    v.y = (unsigned)o[2] | ((unsigned)o[3] << 16);
    v.z = (unsigned)o[4] | ((unsigned)o[5] << 16);
    v.w = (unsigned)o[6] | ((unsigned)o[7] << 16);
    ((uint4*)W0s)[gid] = v;
  }

  __shared__ int lc[NTYPES], lbase[NTYPES];
  if (tid < NTYPES) lc[tid] = 0;
  __syncthreads();
  const int t  = Z[gid];                 // grid 512*256 == N exactly
  const int my = atomicAdd(&lc[t], 1);
  __syncthreads();
  if (tid < NTYPES) lbase[tid] = lc[tid] ? atomicAdd(&cnt[tid], lc[tid]) : 0;
  __syncthreads();
  perm[t * N_ATOMS + lbase[t] + my] = gid;
}

// ---------------------------------------------------------------------------
// half-tile staging: 8 float4 (32 VGPRs) per phase. Half #1's ISSUE is
// hoisted BEFORE the K-loop (15k cycles of coverage); its convert+ds_write
// waits on a counted vmcnt after the K-loop. Half #2 is issued before the
// epilogue and stored after it. No wait in this kernel is covered by less
// than ~2k cycles of independent work.
// ---------------------------------------------------------------------------
__device__ __forceinline__ void issue_half(float4* st, const float* q,
                                           int atom, int c4, int h) {
  const float* p = q + (size_t)atom * DQ + c4 * 64 + h * 32;
#pragma unroll
  for (int i = 0; i < 8; ++i) st[i] = *(const float4*)(p + i * 4);
}

__device__ __forceinline__ void store_half(
    const float4* st, unsigned short (*A)[TILE_M][8], int row, int c4, int h) {
#pragma unroll
  for (int i2 = 0; i2 < 4; ++i2) {
    const int k = c4 * 64 + h * 32 + i2 * 8;   // k & 7 == 0 -> 16B-aligned
    uint4 vv;
    vv.x = (unsigned)f2bf(st[2*i2].x)   | ((unsigned)f2bf(st[2*i2].y)   << 16);
    vv.y = (unsigned)f2bf(st[2*i2].z)   | ((unsigned)f2bf(st[2*i2].w)   << 16);
    vv.z = (unsigned)f2bf(st[2*i2+1].x) | ((unsigned)f2bf(st[2*i2+1].y) << 16);
    vv.w = (unsigned)f2bf(st[2*i2+1].z) | ((unsigned)f2bf(st[2*i2+1].w) << 16);
    *(uint4*)&A[k >> 3][row][0] = vv;
  }
}

// ---------------------------------------------------------------------------
// gemm_persist: 512 persistent blocks, static stride-512 tiles. Per tile:
//   (st#1 for tile n+1 already in flight, issued end of prev iteration)
//   issue b0/W1 -> K-loop (covers st#1 + b0/W1 latency) -> store#1 ->
//   issue st#2 -> EPI0+EPI1 (covers st#2) -> store#2 -> barrier ->
//   out-write -> advance (perm prefetch + issue st#1 for tile n+2).
// ---------------------------------------------------------------------------
__global__ __launch_bounds__(256, 2) void gemm_persist(
    const float* __restrict__ q, const int* __restrict__ perm,
    const int* __restrict__ cnt,
    const unsigned short* __restrict__ W0s,
    const float* __restrict__ b0g, const float* __restrict__ W1,
    const float* __restrict__ b1p, float* __restrict__ out)
{
  __shared__ unsigned short Alds[2][DQ / 8][TILE_M][8];  // 64 KB
  __shared__ float Fws[2][4][TILE_M];                    // 2 KB

  const int tid = threadIdx.x;
  const int l = tid & 63, w = tid >> 6;
  const int half = l >> 5, ln = l & 31;
  const int row = tid >> 2, c4 = tid & 3;
  const int bx = (int)blockIdx.x;

  const int c0 = cnt[0], c1 = cnt[1], c2 = cnt[2], c3 = cnt[3];
  const int n0 = (c0 + 63) >> 6, n1 = (c1 + 63) >> 6;
  const int n2 = (c2 + 63) >> 6, n3 = (c3 + 63) >> 6;
  const int p1 = n0, p2 = n0 + n1, p3 = n0 + n1 + n2;
  const int total = n0 + n1 + n2 + n3;   // 2048..2051 (>= GRID)
  const float b1v = b1p[0];

#define DECODE(v, T, J0, CT) do {                                   \
    T = ((v) >= p1) + ((v) >= p2) + ((v) >= p3);                    \
    const int pre_ = (T == 0) ? 0 : (T == 1) ? p1 : (T == 2) ? p2 : p3; \
    CT = (T == 0) ? c0 : (T == 1) ? c1 : (T == 2) ? c2 : c3;        \
    J0 = ((v) - pre_) * TILE_M; } while (0)

  // epilogue half MT: consumes acc[MT][*], writes Fws rows MT*32..MT*32+31
#define EPI_HALF(MT) do {                                                     \
    _Pragma("unroll")                                                         \
    for (int r = 0; r < 16; ++r) {                                            \
      float s = 0.f;                                                          \
      _Pragma("unroll")                                                       \
      for (int nt = 0; nt < 4; ++nt)                                          \
        s += w1v[nt] * fast_tanh(acc[MT][nt][r] + b0v[nt]);                   \
      s += __shfl_xor(s, 1);                                                  \
      s += __shfl_xor(s, 2);                                                  \
      s += __shfl_xor(s, 4);                                                  \
      s += __shfl_xor(s, 8);                                                  \
      s += __shfl_xor(s, 16);                                                 \
      if (ln == 0)                                                            \
        Fws[cur][w][(MT) * 32 + (r & 3) + 8 * (r >> 2) + 4 * half] = s;       \
    }                                                                         \
  } while (0)

  // ---- prologue: tile bx into buf 0 (total >= 2048 > GRID, always valid) --
  int vt_cur = bx;
  int t_cur, j0_cur, ct_cur;
  DECODE(vt_cur, t_cur, j0_cur, ct_cur);

  float4 st[8];
  {
    int atom = 0;
    if (j0_cur + row < ct_cur) atom = perm[t_cur * N_ATOMS + j0_cur + row];
    issue_half(st, q, atom, c4, 0);
    store_half(st, Alds[0], row, c4, 0);
    issue_half(st, q, atom, c4, 1);
    store_half(st, Alds[0], row, c4, 1);
  }

  int vt_nxt = bx + GRID;
  int t_nxt = 0, j0_nxt = 0, ct_nxt = 0, anext = 0;
  if (vt_nxt < total) {
    DECODE(vt_nxt, t_nxt, j0_nxt, ct_nxt);
    if (j0_nxt + row < ct_nxt) anext = perm[t_nxt * N_ATOMS + j0_nxt + row];
    issue_half(st, q, anext, c4, 0);   // st#1 for tile n+1, in flight
  }
  __syncthreads();

  int cur = 0;

  while (vt_cur < total) {
    const bool have_nxt = (vt_nxt < total);

    // ---- a. b0/W1 for the CURRENT tile's epilogue (issued pre-K-loop:
    // the whole K-loop covers their latency) ----
    float b0v[4], w1v[4];
#pragma unroll
    for (int nt = 0; nt < 4; ++nt) {
      const int c = w * 128 + nt * 32 + ln;
      b0v[nt] = b0g[t_cur * H1 + c];
      w1v[nt] = W1[t_cur * H1 + c];
    }

    // ---- b. K-loop on Alds[cur], B from L2 (pre-swizzled W0s) ----
    f32x16 acc[2][4];
#pragma unroll
    for (int mt = 0; mt < 2; ++mt)
#pragma unroll
      for (int nt = 0; nt < 4; ++nt) acc[mt][nt] = (f32x16)0.0f;

    const unsigned short* Bt = W0s + (size_t)t_cur * (DQ * H1);
    const unsigned short* Bbase = Bt + (size_t)(w * 128 + ln) * 8;

    __builtin_amdgcn_s_setprio(1);
#pragma unroll 4
    for (int step = 0; step < 16; ++step) {
      const int kg = 2 * step + half;
      const bf16x8 a0 = *(const bf16x8*)&Alds[cur][kg][ln][0];
      const bf16x8 a1 = *(const bf16x8*)&Alds[cur][kg][32 + ln][0];
      const unsigned short* bptr = Bbase + (size_t)kg * (H1 * 8);
      const bf16x8 b0f = *(const bf16x8*)(bptr);
      const bf16x8 b1f = *(const bf16x8*)(bptr + 32 * 8);
      const bf16x8 b2f = *(const bf16x8*)(bptr + 64 * 8);
      const bf16x8 b3f = *(const bf16x8*)(bptr + 96 * 8);
      acc[0][0] = __builtin_amdgcn_mfma_f32_32x32x16_bf16(a0, b0f, acc[0][0], 0, 0, 0);
      acc[1][0] = __builtin_amdgcn_mfma_f32_32x32x16_bf16(a1, b0f, acc[1][0], 0, 0, 0);
      acc[0][1] = __builtin_amdgcn_mfma_f32_32x32x16_bf16(a0, b1f, acc[0][1], 0, 0, 0);
      acc[1][1] = __builtin_amdgcn_mfma_f32_32x32x16_bf16(a1, b1f, acc[1][1], 0, 0, 0);
      acc[0][2] = __builtin_amdgcn_mfma_f32_32x32x16_bf16(a0, b2f, acc[0][2], 0, 0, 0);
      acc[1][2] = __builtin_amdgcn_mfma_f32_32x32x16_bf16(a1, b2f, acc[1][2], 0, 0, 0);
      acc[0][3] = __builtin_amdgcn_mfma_f32_32x32x16_bf16(a0, b3f, acc[0][3], 0, 0, 0);
      acc[1][3] = __builtin_amdgcn_mfma_f32_32x32x16_bf16(a1, b3f, acc[1][3], 0, 0, 0);
    }
    __builtin_amdgcn_s_setprio(0);

    // ---- c. store half #1 (wait on st#1 is counted; K-loop covered it) ----
    if (have_nxt) store_half(st, Alds[cur ^ 1], row, c4, 0);

    // ---- d. issue half #2 (reuses st regs; epilogue covers it) ----
    if (have_nxt) issue_half(st, q, anext, c4, 1);

    // ---- e. epilogue: h = tanh(acc + b0), partial F = h . W1 ----
    EPI_HALF(0);
    EPI_HALF(1);

    // ---- f. store half #2 (covered by EPI0+EPI1) ----
    if (have_nxt) store_half(st, Alds[cur ^ 1], row, c4, 1);

    __syncthreads();   // Fws[cur] + Alds[cur^1] ready

    // ---- g. out-write from Fws[cur] ----
    if (tid < TILE_M && j0_cur + tid < ct_cur) {
      const int a = perm[t_cur * N_ATOMS + j0_cur + tid];
      out[a] = Fws[cur][0][tid] + Fws[cur][1][tid] + Fws[cur][2][tid]
             + Fws[cur][3][tid] + b1v;
    }

    // ---- h. advance; prefetch perm + issue st#1 for tile n+2 ----
    vt_cur = vt_nxt;
    if (have_nxt) {
      t_cur = t_nxt; j0_cur = j0_nxt; ct_cur = ct_nxt;
      vt_nxt += GRID;
      anext = 0;
      if (vt_nxt < total) {
        DECODE(vt_nxt, t_nxt, j0_nxt, ct_nxt);
        if (j0_nxt + row < ct_nxt) anext = perm[t_nxt * N_ATOMS + j0_nxt + row];
        issue_half(st, q, anext, c4, 0);   // in flight across next K-loop
      }
    }
    cur ^= 1;
  }
#undef DECODE
#undef EPI_HALF
}

extern "C" void kernel_launch(void* const* d_in, const int* in_sizes, int n_in,
                              void* d_out, int out_size, void* d_ws, size_t ws_size,
                              hipStream_t stream) {
  const float* q  = (const float*)d_in[0];
  const int*   Z  = (const int*)d_in[1];
  const float* W0 = (const float*)d_in[2];
  const float* b0 = (const float*)d_in[3];
  const float* W1 = (const float*)d_in[4];
  const float* b1 = (const float*)d_in[5];
  float* out = (float*)d_out;

  char* ws = (char*)d_ws;
  int* hdr    = (int*)(ws);                        // cnt[4] + pad
  int* cnt    = hdr;
  int* perm   = (int*)(ws + 64);                   // 4*N ints = 2 MB
  unsigned short* W0s =
      (unsigned short*)(ws + 64 + (size_t)NTYPES * N_ATOMS * 4);  // 1 MB

  hipLaunchKernelGGL(init_kernel, dim3(1), dim3(64), 0, stream, hdr);
  hipLaunchKernelGGL(prep_kernel, dim3(512), dim3(256), 0, stream,
                     W0, Z, W0s, perm, cnt);
  hipLaunchKernelGGL(gemm_persist, dim3(GRID), dim3(256), 0, stream,
                     q, perm, cnt, W0s, b0, W1, b1, out);
}

// Round 11
// 269.984 us; speedup vs baseline: 1.0188x; 1.0188x over previous
//
#include <hip/hip_runtime.h>
#include <hip/hip_bf16.h>

#define N_ATOMS 131072
#define DQ 256
#define H1 512
#define NTYPES 4
#define TILE_M 64
#define GRID 512    // persistent, 2/CU; static stride-512 tile schedule

typedef __bf16 bf16x8 __attribute__((ext_vector_type(8)));
typedef float f32x16 __attribute__((ext_vector_type(16)));

__device__ __forceinline__ unsigned short f2bf(float f) {
  unsigned int u = __builtin_bit_cast(unsigned int, f);
  u += 0x7fffu + ((u >> 16) & 1u);   // round-to-nearest-even (inputs finite)
  return (unsigned short)(u >> 16);
}

__device__ __forceinline__ float fast_tanh(float x) {
  float e = __expf(2.0f * x);
  return 1.0f - 2.0f * __builtin_amdgcn_rcpf(e + 1.0f);
}

// ---------------------------------------------------------------------------
// init: zero hdr + ALL of out (cleanup rows are accumulated via atomicAdd,
// so their out slots must start at 0; main rows overwrite, harmless).
// ---------------------------------------------------------------------------
__global__ __launch_bounds__(256) void init_kernel(int* __restrict__ hdr,
                                                   float* __restrict__ out) {
  const int gid = blockIdx.x * 256 + threadIdx.x;
  if (gid < 16) hdr[gid] = 0;
  for (int i = gid; i < N_ATOMS; i += 512 * 256) out[i] = 0.0f;
}

// ---------------------------------------------------------------------------
// prep (fused): (a) W0 fp32 -> bf16 pre-swizzled [t][k/8][n][8k],
// (b) block-aggregated scatter of atom ids into FIXED per-type perm regions
// (perm[t*N + j], j < cnt[t]).
// ---------------------------------------------------------------------------
__global__ __launch_bounds__(256) void prep_kernel(
    const float* __restrict__ W0, const int* __restrict__ Z,
    unsigned short* __restrict__ W0s, int* __restrict__ perm,
    int* __restrict__ cnt)
{
  const int b = blockIdx.x, tid = threadIdx.x;
  const int gid = b * 256 + tid;

  if (gid < NTYPES * (DQ / 8) * H1) {   // 65536 16-byte chunks
    const int n  = gid & (H1 - 1);
    const int kg = (gid >> 9) & 31;
    const int t  = gid >> 14;
    const float* src = W0 + ((size_t)(t * DQ + kg * 8) * H1 + n);
    unsigned short o[8];
#pragma unroll
    for (int j = 0; j < 8; ++j) o[j] = f2bf(src[(size_t)j * H1]);
    uint4 v;
    v.x = (unsigned)o[0] | ((unsigned)o[1] << 16);
    v.y = (unsigned)o[2] | ((unsigned)o[3] << 16);
    v.z = (unsigned)o[4] | ((unsigned)o[5] << 16);
    v.w = (unsigned)o[6] | ((unsigned)o[7] << 16);
    ((uint4*)W0s)[gid] = v;
  }

  __shared__ int lc[NTYPES], lbase[NTYPES];
  if (tid < NTYPES) lc[tid] = 0;
  __syncthreads();
  const int t  = Z[gid];                 // grid 512*256 == N exactly
  const int my = atomicAdd(&lc[t], 1);
  __syncthreads();
  if (tid < NTYPES) lbase[tid] = lc[tid] ? atomicAdd(&cnt[tid], lc[tid]) : 0;
  __syncthreads();
  perm[t * N_ATOMS + lbase[t] + my] = gid;
}

// ---------------------------------------------------------------------------
// half-tile staging: 8 float4 (32 VGPRs) per phase, consumed before the next
// phase is issued (v5's spill lesson: never 64 staging VGPRs live alongside
// the 128-AGPR accumulator).
// ---------------------------------------------------------------------------
__device__ __forceinline__ void issue_half(float4* st, const float* q,
                                           int atom, int c4, int h) {
  const float* p = q + (size_t)atom * DQ + c4 * 64 + h * 32;
#pragma unroll
  for (int i = 0; i < 8; ++i) st[i] = *(const float4*)(p + i * 4);
}

__device__ __forceinline__ void store_half(
    const float4* st, unsigned short (*A)[TILE_M][8], int row, int c4, int h) {
#pragma unroll
  for (int i2 = 0; i2 < 4; ++i2) {
    const int k = c4 * 64 + h * 32 + i2 * 8;   // k & 7 == 0 -> 16B-aligned
    uint4 vv;
    vv.x = (unsigned)f2bf(st[2*i2].x)   | ((unsigned)f2bf(st[2*i2].y)   << 16);
    vv.y = (unsigned)f2bf(st[2*i2].z)   | ((unsigned)f2bf(st[2*i2].w)   << 16);
    vv.z = (unsigned)f2bf(st[2*i2+1].x) | ((unsigned)f2bf(st[2*i2+1].y) << 16);
    vv.w = (unsigned)f2bf(st[2*i2+1].z) | ((unsigned)f2bf(st[2*i2+1].w) << 16);
    *(uint4*)&A[k >> 3][row][0] = vv;
  }
}

// ---------------------------------------------------------------------------
// gemm_persist: MAIN tile space = floor(c_t/64) per type (~2046 tiles) ->
// every block gets <= 4 tiles, NO 5th-tile straggler (rounds 6-10: dur = 5T
// while the majority finished at 4T). All main rows are always valid (no
// bounds checks). The <=252 remainder rows (c_t mod 64, <=4 types) are done
// by 32 CLEANUP units (8 col-groups x 64 cols per partial type; ~T/8 each)
// on blocks 0..31 BEFORE their main tiles, accumulated into pre-zeroed out
// via atomicAdd (F is column-separable). Makespan 5T -> ~4.15T.
// ---------------------------------------------------------------------------
__global__ __launch_bounds__(256, 2) void gemm_persist(
    const float* __restrict__ q, const int* __restrict__ perm,
    const int* __restrict__ cnt,
    const unsigned short* __restrict__ W0s,
    const float* __restrict__ b0g, const float* __restrict__ W1,
    const float* __restrict__ b1p, float* __restrict__ out)
{
  __shared__ unsigned short Alds[2][DQ / 8][TILE_M][8];  // 64 KB
  __shared__ float Fws[2][4][TILE_M];                    // 2 KB

  const int tid = threadIdx.x;
  const int l = tid & 63, w = tid >> 6;
  const int half = l >> 5, ln = l & 31;
  const int row = tid >> 2, c4 = tid & 3;
  const int bx = (int)blockIdx.x;

  const int c0 = cnt[0], c1 = cnt[1], c2 = cnt[2], c3 = cnt[3];
  const int n0f = c0 >> 6, n1f = c1 >> 6, n2f = c2 >> 6, n3f = c3 >> 6;
  const int p1 = n0f, p2 = n0f + n1f, p3 = n0f + n1f + n2f;
  const int total = n0f + n1f + n2f + n3f;   // ~2046 full tiles (>= GRID)
  const float b1v = b1p[0];

#define DECODE(v, T, J0) do {                                       \
    T = ((v) >= p1) + ((v) >= p2) + ((v) >= p3);                    \
    const int pre_ = (T == 0) ? 0 : (T == 1) ? p1 : (T == 2) ? p2 : p3; \
    J0 = ((v) - pre_) * TILE_M; } while (0)

#define EPI_HALF(MT) do {                                                     \
    _Pragma("unroll")                                                         \
    for (int r = 0; r < 16; ++r) {                                            \
      float s = 0.f;                                                          \
      _Pragma("unroll")                                                       \
      for (int nt = 0; nt < 4; ++nt)                                          \
        s += w1v[nt] * fast_tanh(acc[MT][nt][r] + b0v[nt]);                   \
      s += __shfl_xor(s, 1);                                                  \
      s += __shfl_xor(s, 2);                                                  \
      s += __shfl_xor(s, 4);                                                  \
      s += __shfl_xor(s, 8);                                                  \
      s += __shfl_xor(s, 16);                                                 \
      if (ln == 0)                                                            \
        Fws[cur][w][(MT) * 32 + (r & 3) + 8 * (r >> 2) + 4 * half] = s;       \
    }                                                                         \
  } while (0)

  // =========================================================================
  // CLEANUP (blocks 0..31): unit = (partial-type rank pr = bx>>3, col-group
  // cg = bx&7 -> cols cg*64..+64). Rows [ct & ~63, ct). Wave w: rowgrp=w&1
  // (rows rowgrp*32..+32), colgrp=w>>1 (cols cg*64+colgrp*32..+32).
  // =========================================================================
  if (bx < 32) {
    const int pr = bx >> 3, cg = bx & 7;
    int tt = -1, seen = 0;
#pragma unroll
    for (int t = 0; t < NTYPES; ++t) {
      const int ct_ = (t == 0) ? c0 : (t == 1) ? c1 : (t == 2) ? c2 : c3;
      if (ct_ & 63) { if (seen == pr) tt = t; ++seen; }
    }
    if (tt >= 0) {
      const int ct  = (tt == 0) ? c0 : (tt == 1) ? c1 : (tt == 2) ? c2 : c3;
      const int base = ct & ~63;          // first remainder row
      // stage (masked; invalid rows load a valid dummy row, never written)
      {
        const int aj = base + row;
        const int atom = perm[tt * N_ATOMS + ((aj < ct) ? aj : base)];
        float4 st[8];
        issue_half(st, q, atom, c4, 0);
        store_half(st, Alds[0], row, c4, 0);
        issue_half(st, q, atom, c4, 1);
        store_half(st, Alds[0], row, c4, 1);
      }
      __syncthreads();

      const int rowgrp = w & 1, colgrp = w >> 1;
      const int col = cg * 64 + colgrp * 32 + ln;
      const unsigned short* Bt = W0s + (size_t)tt * (DQ * H1);
      const unsigned short* Bbase = Bt + (size_t)col * 8;

      f32x16 acc1 = (f32x16)0.0f;
#pragma unroll 4
      for (int step = 0; step < 16; ++step) {
        const int kg = 2 * step + half;
        const bf16x8 a = *(const bf16x8*)&Alds[0][kg][rowgrp * 32 + ln][0];
        const bf16x8 bfr = *(const bf16x8*)(Bbase + (size_t)kg * (H1 * 8));
        acc1 = __builtin_amdgcn_mfma_f32_32x32x16_bf16(a, bfr, acc1, 0, 0, 0);
      }

      const float b0v1 = b0g[tt * H1 + col];
      const float w1v1 = W1[tt * H1 + col];
#pragma unroll
      for (int r = 0; r < 16; ++r) {
        float s = w1v1 * fast_tanh(acc1[r] + b0v1);
        s += __shfl_xor(s, 1);
        s += __shfl_xor(s, 2);
        s += __shfl_xor(s, 4);
        s += __shfl_xor(s, 8);
        s += __shfl_xor(s, 16);
        if (ln == 0)
          Fws[0][colgrp][rowgrp * 32 + (r & 3) + 8 * (r >> 2) + 4 * half] = s;
      }
      __syncthreads();

      if (tid < TILE_M) {
        const int aj = base + tid;
        if (aj < ct) {
          const float part = Fws[0][0][tid] + Fws[0][1][tid]
                           + ((cg == 0) ? b1v : 0.0f);
          atomicAdd(&out[perm[tt * N_ATOMS + aj]], part);
        }
      }
      // no trailing barrier needed: main prologue only writes Alds[0] (all
      // cleanup reads of Alds[0] completed before the post-K-loop barrier),
      // and Fws is not written again until after the prologue barrier.
    }
  }

  // =========================================================================
  // MAIN loop: static stride-GRID tiles over the full-tile space; all rows
  // valid, no bounds checks. Body identical to the round-6 123 us structure.
  // =========================================================================
  int vt_cur = bx;
  int t_cur, j0_cur;
  DECODE(vt_cur, t_cur, j0_cur);

  float4 st[8];
  {
    const int atom = perm[t_cur * N_ATOMS + j0_cur + row];
    issue_half(st, q, atom, c4, 0);
    store_half(st, Alds[0], row, c4, 0);
    issue_half(st, q, atom, c4, 1);
    store_half(st, Alds[0], row, c4, 1);
  }
  __syncthreads();

  int vt_nxt = bx + GRID;
  int t_nxt = 0, j0_nxt = 0, anext = 0;
  if (vt_nxt < total) {
    DECODE(vt_nxt, t_nxt, j0_nxt);
    anext = perm[t_nxt * N_ATOMS + j0_nxt + row];
  }
  int cur = 0;

  while (vt_cur < total) {
    f32x16 acc[2][4];
#pragma unroll
    for (int mt = 0; mt < 2; ++mt)
#pragma unroll
      for (int nt = 0; nt < 4; ++nt) acc[mt][nt] = (f32x16)0.0f;

    const unsigned short* Bt = W0s + (size_t)t_cur * (DQ * H1);
    const unsigned short* Bbase = Bt + (size_t)(w * 128 + ln) * 8;

    __builtin_amdgcn_s_setprio(1);
#pragma unroll 4
    for (int step = 0; step < 16; ++step) {
      const int kg = 2 * step + half;
      const bf16x8 a0 = *(const bf16x8*)&Alds[cur][kg][ln][0];
      const bf16x8 a1 = *(const bf16x8*)&Alds[cur][kg][32 + ln][0];
      const unsigned short* bptr = Bbase + (size_t)kg * (H1 * 8);
      const bf16x8 b0f = *(const bf16x8*)(bptr);
      const bf16x8 b1f = *(const bf16x8*)(bptr + 32 * 8);
      const bf16x8 b2f = *(const bf16x8*)(bptr + 64 * 8);
      const bf16x8 b3f = *(const bf16x8*)(bptr + 96 * 8);
      acc[0][0] = __builtin_amdgcn_mfma_f32_32x32x16_bf16(a0, b0f, acc[0][0], 0, 0, 0);
      acc[1][0] = __builtin_amdgcn_mfma_f32_32x32x16_bf16(a1, b0f, acc[1][0], 0, 0, 0);
      acc[0][1] = __builtin_amdgcn_mfma_f32_32x32x16_bf16(a0, b1f, acc[0][1], 0, 0, 0);
      acc[1][1] = __builtin_amdgcn_mfma_f32_32x32x16_bf16(a1, b1f, acc[1][1], 0, 0, 0);
      acc[0][2] = __builtin_amdgcn_mfma_f32_32x32x16_bf16(a0, b2f, acc[0][2], 0, 0, 0);
      acc[1][2] = __builtin_amdgcn_mfma_f32_32x32x16_bf16(a1, b2f, acc[1][2], 0, 0, 0);
      acc[0][3] = __builtin_amdgcn_mfma_f32_32x32x16_bf16(a0, b3f, acc[0][3], 0, 0, 0);
      acc[1][3] = __builtin_amdgcn_mfma_f32_32x32x16_bf16(a1, b3f, acc[1][3], 0, 0, 0);
    }
    __builtin_amdgcn_s_setprio(0);

    const bool have_nxt = (vt_nxt < total);

    float b0v[4], w1v[4];
#pragma unroll
    for (int nt = 0; nt < 4; ++nt) {
      const int c = w * 128 + nt * 32 + ln;
      b0v[nt] = b0g[t_cur * H1 + c];
      w1v[nt] = W1[t_cur * H1 + c];
    }

    if (have_nxt) issue_half(st, q, anext, c4, 0);
    EPI_HALF(0);
    if (have_nxt) store_half(st, Alds[cur ^ 1], row, c4, 0);

    if (have_nxt) issue_half(st, q, anext, c4, 1);
    EPI_HALF(1);
    if (have_nxt) store_half(st, Alds[cur ^ 1], row, c4, 1);

    __syncthreads();   // Fws[cur] + Alds[cur^1] ready

    if (tid < TILE_M) {
      const int a = perm[t_cur * N_ATOMS + j0_cur + tid];
      out[a] = Fws[cur][0][tid] + Fws[cur][1][tid] + Fws[cur][2][tid]
             + Fws[cur][3][tid] + b1v;
    }

    vt_cur = vt_nxt;
    if (have_nxt) {
      t_cur = t_nxt; j0_cur = j0_nxt;
      vt_nxt += GRID;
      if (vt_nxt < total) {
        DECODE(vt_nxt, t_nxt, j0_nxt);
        anext = perm[t_nxt * N_ATOMS + j0_nxt + row];
      }
    }
    cur ^= 1;
  }
#undef DECODE
#undef EPI_HALF
}

extern "C" void kernel_launch(void* const* d_in, const int* in_sizes, int n_in,
                              void* d_out, int out_size, void* d_ws, size_t ws_size,
                              hipStream_t stream) {
  const float* q  = (const float*)d_in[0];
  const int*   Z  = (const int*)d_in[1];
  const float* W0 = (const float*)d_in[2];
  const float* b0 = (const float*)d_in[3];
  const float* W1 = (const float*)d_in[4];
  const float* b1 = (const float*)d_in[5];
  float* out = (float*)d_out;

  char* ws = (char*)d_ws;
  int* hdr    = (int*)(ws);                        // cnt[4] + pad
  int* cnt    = hdr;
  int* perm   = (int*)(ws + 64);                   // 4*N ints = 2 MB
  unsigned short* W0s =
      (unsigned short*)(ws + 64 + (size_t)NTYPES * N_ATOMS * 4);  // 1 MB

  hipLaunchKernelGGL(init_kernel, dim3(512), dim3(256), 0, stream, hdr, out);
  hipLaunchKernelGGL(prep_kernel, dim3(512), dim3(256), 0, stream,
                     W0, Z, W0s, perm, cnt);
  hipLaunchKernelGGL(gemm_persist, dim3(GRID), dim3(256), 0, stream,
                     q, perm, cnt, W0s, b0, W1, b1, out);
}